// Round 13
// baseline (541.266 us; speedup 1.0000x reference)
//
#include <hip/hip_runtime.h>
#include <hip/hip_bf16.h>
#include <math.h>

#define BATCH 8
#define NPTS  1024
#define DIM   1024
#define HID   64
#define KNN   20
#define NMAT  16
#define KPACK 3072   // 3 bf16 segments stored contiguously per row: k = seg*1024 + d

typedef __attribute__((ext_vector_type(8))) short short8;
typedef __attribute__((ext_vector_type(4))) float floatx4;

__device__ __forceinline__ const float* mat_base(const float* f1, const float* f2, int m) {
    return (m < BATCH) ? (f1 + (size_t)m * NPTS * DIM)
                       : (f2 + (size_t)(m - BATCH) * NPTS * DIM);
}

__device__ __forceinline__ unsigned short f2bf_bits(float v) {
    __hip_bfloat16 h = __float2bfloat16(v);   // RNE
    return *(unsigned short*)&h;
}
__device__ __forceinline__ float bfbits2f(unsigned short b) {
    union { unsigned u; float f; } c; c.u = ((unsigned)b) << 16; return c.f;
}

// ---------------- K1: FUSED 3-way bf16 split + squared norms + y = f @ W1a ----------------
// R10 version (proven): 512 threads, 32-k chunks, 8 waves/CU.
__global__ __launch_bounds__(512) void split_ymlp_kernel(const float* __restrict__ f1,
                                                         const float* __restrict__ f2,
                                                         const float* __restrict__ W,
                                                         unsigned short* __restrict__ H,
                                                         float* __restrict__ sq,
                                                         float* __restrict__ y) {
    int row0 = blockIdx.x * 64;                 // 64-row blocks never straddle matrices
    int m = row0 >> 10;
    const float* A = mat_base(f1, f2, m) + (size_t)(row0 & (NPTS - 1)) * DIM;
    unsigned short* Hb = H + (size_t)row0 * KPACK;
    __shared__ float As[64][36];                // 32 k-cols + 4 pad
    __shared__ float Ws[32][68];                // 32 k-rows x 64 cols + 4 pad
    int tid = threadIdx.x;                      // 0..511
    int r = tid >> 3, cq = (tid & 7) * 4;       // load map: row r (8 thr/row), cols cq..cq+3
    int ty = tid >> 4, tx = tid & 15;           // GEMM map: rows ty*2..+1, cols tx*4..+3
    float acc[2][4];
    #pragma unroll
    for (int i = 0; i < 2; ++i)
        #pragma unroll
        for (int j = 0; j < 4; ++j) acc[i][j] = 0.f;
    float sqp = 0.f;
    unsigned short* Hr = Hb + (size_t)r * KPACK + cq;

    for (int kk = 0; kk < DIM; kk += 32) {
        float4 a = *(const float4*)&A[(size_t)r * DIM + kk + cq];
        // ---- split (bitwise-identical elementwise chain) ----
        {
            float vv[4] = {a.x, a.y, a.z, a.w};
            unsigned short h1[4], h2[4], h3[4];
            #pragma unroll
            for (int c = 0; c < 4; ++c) {
                unsigned short b1 = f2bf_bits(vv[c]);
                float r1 = vv[c] - bfbits2f(b1);
                unsigned short b2 = f2bf_bits(r1);
                float r2 = r1 - bfbits2f(b2);
                unsigned short b3 = f2bf_bits(r2);
                h1[c] = b1; h2[c] = b2; h3[c] = b3;
            }
            *(ushort4*)&Hr[kk]        = *(ushort4*)&h1[0];
            *(ushort4*)&Hr[1024 + kk] = *(ushort4*)&h2[0];
            *(ushort4*)&Hr[2048 + kk] = *(ushort4*)&h3[0];
            sqp += a.x * a.x + a.y * a.y + a.z * a.z + a.w * a.w;
        }
        // ---- GEMM staging ----
        *(float4*)&As[r][cq] = a;
        {
            int d = tid >> 4, hh = (tid & 15) * 4;   // 32 k-rows x 16 col-groups
            *(float4*)&Ws[d][hh] = *(const float4*)&W[(size_t)(kk + d) * HID + hh];
        }
        __syncthreads();
        #pragma unroll
        for (int k = 0; k < 32; ++k) {
            float av[2];
            #pragma unroll
            for (int ii = 0; ii < 2; ++ii) av[ii] = As[ty * 2 + ii][k];
            float4 w = *(const float4*)&Ws[k][tx * 4];
            #pragma unroll
            for (int ii = 0; ii < 2; ++ii) {
                acc[ii][0] += av[ii] * w.x;
                acc[ii][1] += av[ii] * w.y;
                acc[ii][2] += av[ii] * w.z;
                acc[ii][3] += av[ii] * w.w;
            }
        }
        __syncthreads();
    }
    sqp += __shfl_down(sqp, 4);
    sqp += __shfl_down(sqp, 2);
    sqp += __shfl_down(sqp, 1);
    if ((tid & 7) == 0) sq[row0 + r] = sqp;
    #pragma unroll
    for (int ii = 0; ii < 2; ++ii)
        *(float4*)&y[(size_t)(row0 + ty * 2 + ii) * HID + tx * 4] = *(float4*)&acc[ii][0];
}

// ---------------- K2: Gram -> squared distances via bf16 MFMA ----------------
// R13: PASS-SPLIT LAUNCH for forced per-XCD L2 residency. Diagnosis: FETCH ~95MB ==
// compulsory, so the 905MB staged re-reads are cache-absorbed but at only ~5 TB/s
// (LLC rate, 905MB/181us) — near-zero L2 hits because each XCD interleaves TWO
// matrices (12.6MB) against 4MB L2. Fix: two stream-ordered launches of 288 blocks;
// pass p: xcd=bid&7, t=bid>>3 (0..35), m=xcd+8p -> ONE matrix (6.3MB) per XCD per
// pass, all 288 blocks co-resident (no dispatch rounds). Kernel-boundary enforces
// the synchronization R5's self-sync hoped for. Same 576 (m,tile) jobs, identical
// per-job code -> dist bitwise identical. Kernel body = R11 (best known: triple-
// buffered B, vmcnt(12) counted pipeline, R9 prologue drain). Bounds-3 forbidden
// (R6 flake); 128^2 tiles proven optimal (R4/R9).
#define GRAM_STEP(CURAF, NXTAF, CBUF, NBUF, KN, ISSUE, WAITOP)                             \
  {                                                                                        \
    if (ISSUE) {                                                                           \
      _Pragma("unroll")                                                                    \
      for (int s = 0; s < 3; ++s)                                                          \
        NXTAF[s] = *(const short8*)&Hm[(size_t)(ti + (w << 4) + r16) * KPACK               \
                                       + (size_t)(s << 10) + (KN) + (kc << 3)];            \
      _Pragma("unroll")                                                                    \
      for (int c = 0; c < 3; ++c) {                                                        \
        int ca = w * 3 + c; int seg = ca >> 3; int rb = ca & 7;                            \
        const unsigned short* gb = Hm + (size_t)(tj + rb * 16 + r16) * KPACK               \
                                      + (size_t)(seg << 10) + (KN) + (kc << 3);            \
        __builtin_amdgcn_global_load_lds(                                                  \
            (const __attribute__((address_space(1))) void*)gb,                             \
            (__attribute__((address_space(3))) void*)&Bsl[NBUF][ca * 512], 16, 0, 0);      \
      }                                                                                    \
    }                                                                                      \
    asm volatile(WAITOP ::: "memory");                                                     \
    __builtin_amdgcn_s_barrier();                                                          \
    asm volatile("" ::: "memory");                                                         \
    __builtin_amdgcn_s_setprio(1);                                                         \
    _Pragma("unroll")                                                                      \
    for (int sb = 0; sb < 3; ++sb) {                                                       \
      short8 bf[8];                                                                        \
      _Pragma("unroll")                                                                    \
      for (int b = 0; b < 8; ++b)                                                          \
        bf[b] = *(const short8*)&Bsl[CBUF][(sb * 8 + b) * 512 + lane * 8];                 \
      _Pragma("unroll")                                                                    \
      for (int sa = 0; sa < 3; ++sa) {                                                     \
        if (sa + sb > 2) continue;                                                         \
        _Pragma("unroll")                                                                  \
        for (int b = 0; b < 8; ++b)                                                        \
          acc[b] = __builtin_amdgcn_mfma_f32_16x16x32_bf16(CURAF[sa], bf[b],               \
                                                           acc[b], 0, 0, 0);               \
      }                                                                                    \
    }                                                                                      \
    __builtin_amdgcn_s_setprio(0);                                                         \
    asm volatile("" ::: "memory");                                                         \
    __builtin_amdgcn_s_barrier();                                                          \
  }

__global__ __launch_bounds__(512, 4) void gram_mfma_kernel(const unsigned short* __restrict__ H,
                                                           const float* __restrict__ sq,
                                                           float* __restrict__ dist,
                                                           int pass) {
    int bid = blockIdx.x;                 // 0..287
    int xcd = bid & 7;
    int t = bid >> 3;                     // 0..35 : upper-tri tile index
    int m = xcd + 8 * pass;               // ONE matrix per XCD this pass
    int bi = 0;
    { int a = t; while (a >= 8 - bi) { a -= 8 - bi; ++bi; } t = a; }
    int bj = bi + t;
    int ti = bi << 7, tj = bj << 7;

    const unsigned short* Hm = H + (size_t)m * NPTS * KPACK;

    // B chunks: ca = seg*8 + colblk ; each chunk: [lane(64)][8 shorts] = 1KB (16 cols x 32 k)
    __shared__ __align__(16) unsigned short Bsl[3][24 * 512];   // 3 x 24 KB triple buffer

    int tid = threadIdx.x;
    int w = tid >> 6, lane = tid & 63;   // 8 waves; wave owns rows ti + w*16 .. +15
    int r16 = lane & 15, kc = lane >> 4;

    floatx4 acc[8];
    #pragma unroll
    for (int b = 0; b < 8; ++b) acc[b] = (floatx4)0.f;

    // A fragment triple buffers: wave-private rows (3 segs x 1 rowblock each)
    short8 afA[3], afB[3], afC[3];

    // ---- prologue (grouped: afA | B0-DMA | afB | B1-DMA, then full drain) ----
    #pragma unroll
    for (int s = 0; s < 3; ++s)
        afA[s] = *(const short8*)&Hm[(size_t)(ti + (w << 4) + r16) * KPACK
                                     + (size_t)(s << 10) + (kc << 3)];
    asm volatile("" ::: "memory");
    #pragma unroll
    for (int c = 0; c < 3; ++c) {
        int ca = w * 3 + c; int seg = ca >> 3; int rb = ca & 7;
        const unsigned short* gb = Hm + (size_t)(tj + rb * 16 + r16) * KPACK
                                      + (size_t)(seg << 10) + (kc << 3);
        __builtin_amdgcn_global_load_lds(
            (const __attribute__((address_space(1))) void*)gb,
            (__attribute__((address_space(3))) void*)&Bsl[0][ca * 512], 16, 0, 0);
    }
    asm volatile("" ::: "memory");
    #pragma unroll
    for (int s = 0; s < 3; ++s)
        afB[s] = *(const short8*)&Hm[(size_t)(ti + (w << 4) + r16) * KPACK
                                     + (size_t)(s << 10) + 32 + (kc << 3)];
    asm volatile("" ::: "memory");
    #pragma unroll
    for (int c = 0; c < 3; ++c) {
        int ca = w * 3 + c; int seg = ca >> 3; int rb = ca & 7;
        const unsigned short* gb = Hm + (size_t)(tj + rb * 16 + r16) * KPACK
                                      + (size_t)(seg << 10) + 32 + (kc << 3);
        __builtin_amdgcn_global_load_lds(
            (const __attribute__((address_space(1))) void*)gb,
            (__attribute__((address_space(3))) void*)&Bsl[1][ca * 512], 16, 0, 0);
    }
    // Full drain: slices 0/1 complete before the loop; steps 0/1's vmcnt(12) are
    // no-ops (6/12 outstanding); steady state from step 2 retires exactly one slice.
    asm volatile("s_waitcnt vmcnt(0)" ::: "memory");

    // slices 0..29: compute t, issue t+2, wait vmcnt(12) (t+1,t+2 in flight: 6+6)
    #pragma unroll 1
    for (int t2 = 0; t2 < 30; t2 += 3) {
        GRAM_STEP(afA, afC, 0, 2, (t2 + 2) * 32, 1, "s_waitcnt vmcnt(12)");
        GRAM_STEP(afB, afA, 1, 0, (t2 + 3) * 32, 1, "s_waitcnt vmcnt(12)");
        GRAM_STEP(afC, afB, 2, 1, (t2 + 4) * 32, 1, "s_waitcnt vmcnt(12)");
    }
    // epilogue: slice 30 (slice 31 still in flight), then slice 31
    GRAM_STEP(afA, afC, 0, 2, 0, 0, "s_waitcnt vmcnt(6)");
    GRAM_STEP(afB, afC, 1, 2, 0, 0, "s_waitcnt vmcnt(0)");

    const float* sqm = sq + m * NPTS;
    {
        int i0 = ti + (w << 4) + (lane >> 4) * 4;
        #pragma unroll
        for (int b = 0; b < 8; ++b) {
            int j = tj + b * 16 + (lane & 15);
            float sqj = sqm[j];
            #pragma unroll
            for (int r = 0; r < 4; ++r) {
                int i = i0 + r;
                float v = sqm[i] + sqj - 2.f * acc[b][r];
                if (i == j) v += 1e10f;
                dist[((size_t)m * NPTS + i) * NPTS + j] = v;
                if (bi != bj) dist[((size_t)m * NPTS + j) * NPTS + i] = v;
            }
        }
    }
}

// ---------------- K3: top-k (k=20 smallest), one wave per row, all-register ----------------
__global__ __launch_bounds__(256) void topk_kernel(const float* __restrict__ dist,
                                                   int* __restrict__ knn_idx) {
    int tid = threadIdx.x;
    int wave = tid >> 6, lane = tid & 63;
    int row = blockIdx.x * 4 + wave;
    const float* d = dist + (size_t)row * NPTS;
    float v[16];
    #pragma unroll
    for (int s = 0; s < 16; ++s) v[s] = d[s * 64 + lane];
    int myj = 0;
    for (int sel = 0; sel < KNN; ++sel) {
        float bv = v[0]; int bs = 0;
        #pragma unroll
        for (int s = 1; s < 16; ++s)
            if (v[s] < bv) { bv = v[s]; bs = s; }   // ascending s: lowest j locally on ties
        int bj = bs * 64 + lane;
        #pragma unroll
        for (int off = 1; off < 64; off <<= 1) {
            float ov = __shfl_xor(bv, off);
            int   oj = __shfl_xor(bj, off);
            if (ov < bv || (ov == bv && oj < bj)) { bv = ov; bj = oj; }
        }
        if ((bj & 63) == lane) v[bj >> 6] = 3e38f;  // owner clears
        if (lane == sel) myj = bj;
    }
    if (lane < KNN) knn_idx[(size_t)row * KNN + lane] = myj;
}

// ---------------- K5: t1 = relu(y_i + sum y_n + b1a); h1 = t1 @ W2a + b2a ----------------
// R12 version (proven): 512 threads, 8 waves/CU.
__global__ __launch_bounds__(512) void t1h1_kernel(const float* __restrict__ y,
                                                   const int* __restrict__ knn_idx,
                                                   const float* __restrict__ W,
                                                   const float* __restrict__ bias1,
                                                   const float* __restrict__ bias2,
                                                   float* __restrict__ h1) {
    int row0 = blockIdx.x * 64;
    int m = row0 >> 10;
    __shared__ int nb[64 * KNN];
    __shared__ float t1s[64][65];
    __shared__ float Ws[64][HID];
    __shared__ float b1s[HID], b2s[HID];
    int tid = threadIdx.x;                       // 0..511
    for (int k = tid; k < 64 * KNN; k += 512) nb[k] = knn_idx[(size_t)row0 * KNN + k];
    for (int k = tid; k < 64 * HID; k += 512) Ws[k >> 6][k & 63] = W[k];
    if (tid < HID) { b1s[tid] = bias1[tid]; b2s[tid] = bias2[tid]; }
    __syncthreads();
    {
        int r = tid >> 3, c0 = (tid & 7) * 8;    // 8 threads/row, 8 cols each
        const float* yr = y + (size_t)(row0 + r) * HID + c0;
        float4 a[2];
        #pragma unroll
        for (int q = 0; q < 2; ++q) a[q] = *(const float4*)&yr[q * 4];
        const float* ym = y + (size_t)(m << 10) * HID;
        #pragma unroll
        for (int t = 0; t < KNN; ++t) {
            const float* yn = ym + (size_t)nb[r * KNN + t] * HID + c0;
            #pragma unroll
            for (int q = 0; q < 2; ++q) {
                float4 v = *(const float4*)&yn[q * 4];
                a[q].x += v.x; a[q].y += v.y; a[q].z += v.z; a[q].w += v.w;
            }
        }
        #pragma unroll
        for (int q = 0; q < 2; ++q) {
            int c = c0 + q * 4;
            t1s[r][c + 0] = fmaxf(a[q].x + b1s[c + 0], 0.f);
            t1s[r][c + 1] = fmaxf(a[q].y + b1s[c + 1], 0.f);
            t1s[r][c + 2] = fmaxf(a[q].z + b1s[c + 2], 0.f);
            t1s[r][c + 3] = fmaxf(a[q].w + b1s[c + 3], 0.f);
        }
    }
    __syncthreads();
    int ty = tid >> 4, tx = tid & 15;            // rows ty*2..+1, cols tx*4..+3
    float acc[2][4];
    #pragma unroll
    for (int i = 0; i < 2; ++i)
        #pragma unroll
        for (int j = 0; j < 4; ++j) acc[i][j] = 0.f;
    #pragma unroll
    for (int k = 0; k < HID; ++k) {
        float a[2];
        #pragma unroll
        for (int ii = 0; ii < 2; ++ii) a[ii] = t1s[ty * 2 + ii][k];
        float4 w = *(const float4*)&Ws[k][tx * 4];
        #pragma unroll
        for (int ii = 0; ii < 2; ++ii) {
            acc[ii][0] += a[ii] * w.x;
            acc[ii][1] += a[ii] * w.y;
            acc[ii][2] += a[ii] * w.z;
            acc[ii][3] += a[ii] * w.w;
        }
    }
    #pragma unroll
    for (int ii = 0; ii < 2; ++ii) {
        float o[4];
        #pragma unroll
        for (int jj = 0; jj < 4; ++jj) o[jj] = acc[ii][jj] + b2s[tx * 4 + jj];
        *(float4*)&h1[(size_t)(row0 + ty * 2 + ii) * HID + tx * 4] = *(float4*)&o[0];
    }
}

// ---------------- K6: hs = h1_i + sum h1_n; t2 = relu(hs@W1b+b1b); z = t2@W2b+b2b ----------------
// R12 version (proven): 512 threads, 8 waves/CU.
__global__ __launch_bounds__(512) void t2z_kernel(const float* __restrict__ h1,
                                                  const int* __restrict__ knn_idx,
                                                  const float* __restrict__ W1,
                                                  const float* __restrict__ bias1,
                                                  const float* __restrict__ W2,
                                                  const float* __restrict__ bias2,
                                                  float* __restrict__ z) {
    int row0 = blockIdx.x * 64;
    int m = row0 >> 10;
    __shared__ int nb[64 * KNN];
    __shared__ float hs[64][65];
    __shared__ float t2s[64][65];
    __shared__ float Ws[64][HID];
    __shared__ float b1s[HID], b2s[HID];
    int tid = threadIdx.x;                       // 0..511
    for (int k = tid; k < 64 * KNN; k += 512) nb[k] = knn_idx[(size_t)row0 * KNN + k];
    for (int k = tid; k < 64 * HID; k += 512) Ws[k >> 6][k & 63] = W1[k];
    if (tid < HID) { b1s[tid] = bias1[tid]; b2s[tid] = bias2[tid]; }
    __syncthreads();
    {
        int r = tid >> 3, c0 = (tid & 7) * 8;
        const float* hr = h1 + (size_t)(row0 + r) * HID + c0;
        float4 a[2];
        #pragma unroll
        for (int q = 0; q < 2; ++q) a[q] = *(const float4*)&hr[q * 4];
        const float* hm = h1 + (size_t)(m << 10) * HID;
        #pragma unroll
        for (int t = 0; t < KNN; ++t) {
            const float* hn = hm + (size_t)nb[r * KNN + t] * HID + c0;
            #pragma unroll
            for (int q = 0; q < 2; ++q) {
                float4 v = *(const float4*)&hn[q * 4];
                a[q].x += v.x; a[q].y += v.y; a[q].z += v.z; a[q].w += v.w;
            }
        }
        #pragma unroll
        for (int q = 0; q < 2; ++q) *(float4*)&hs[r][c0 + q * 4] = a[q];
    }
    __syncthreads();
    int ty = tid >> 4, tx = tid & 15;
    float acc[2][4];
    #pragma unroll
    for (int i = 0; i < 2; ++i)
        #pragma unroll
        for (int j = 0; j < 4; ++j) acc[i][j] = 0.f;
    #pragma unroll
    for (int k = 0; k < HID; ++k) {
        float a[2];
        #pragma unroll
        for (int ii = 0; ii < 2; ++ii) a[ii] = hs[ty * 2 + ii][k];
        float4 w = *(const float4*)&Ws[k][tx * 4];
        #pragma unroll
        for (int ii = 0; ii < 2; ++ii) {
            acc[ii][0] += a[ii] * w.x;
            acc[ii][1] += a[ii] * w.y;
            acc[ii][2] += a[ii] * w.z;
            acc[ii][3] += a[ii] * w.w;
        }
    }
    #pragma unroll
    for (int ii = 0; ii < 2; ++ii)
        #pragma unroll
        for (int jj = 0; jj < 4; ++jj)
            t2s[ty * 2 + ii][tx * 4 + jj] = fmaxf(acc[ii][jj] + b1s[tx * 4 + jj], 0.f);
    __syncthreads();
    for (int k = tid; k < 64 * HID; k += 512) Ws[k >> 6][k & 63] = W2[k];
    __syncthreads();
    #pragma unroll
    for (int i = 0; i < 2; ++i)
        #pragma unroll
        for (int j = 0; j < 4; ++j) acc[i][j] = 0.f;
    #pragma unroll
    for (int k = 0; k < HID; ++k) {
        float a[2];
        #pragma unroll
        for (int ii = 0; ii < 2; ++ii) a[ii] = t2s[ty * 2 + ii][k];
        float4 w = *(const float4*)&Ws[k][tx * 4];
        #pragma unroll
        for (int ii = 0; ii < 2; ++ii) {
            acc[ii][0] += a[ii] * w.x;
            acc[ii][1] += a[ii] * w.y;
            acc[ii][2] += a[ii] * w.z;
            acc[ii][3] += a[ii] * w.w;
        }
    }
    #pragma unroll
    for (int ii = 0; ii < 2; ++ii) {
        float o[4];
        #pragma unroll
        for (int jj = 0; jj < 4; ++jj) o[jj] = acc[ii][jj] + b2s[tx * 4 + jj];
        *(float4*)&z[(size_t)(row0 + ty * 2 + ii) * HID + tx * 4] = *(float4*)&o[0];
    }
}

// ---------------- K7: sim = z1 @ z2^T (64x64 tiles, K=64) ----------------
__global__ __launch_bounds__(256) void sim_kernel(const float* __restrict__ z,
                                                  float* __restrict__ logits) {
    int bid = blockIdx.x;
    int b = bid >> 8;
    int tile = bid & 255;
    int ti = (tile >> 4) << 6;
    int tj = (tile & 15) << 6;
    const float* z1 = z + (size_t)b * NPTS * HID;
    const float* z2 = z + (size_t)(BATCH + b) * NPTS * HID;
    __shared__ float Z1[64][68];
    __shared__ float Z2[64][68];
    int tid = threadIdx.x;
    #pragma unroll
    for (int i = 0; i < 4; ++i) {
        int l = tid + i * 256;
        int r = l >> 4, c = (l & 15) * 4;
        *(float4*)&Z1[r][c] = *(const float4*)&z1[(size_t)(ti + r) * HID + c];
        *(float4*)&Z2[r][c] = *(const float4*)&z2[(size_t)(tj + r) * HID + c];
    }
    __syncthreads();
    int ty = tid >> 4, tx = tid & 15;
    float acc[4][4];
    #pragma unroll
    for (int i = 0; i < 4; ++i)
        #pragma unroll
        for (int j = 0; j < 4; ++j) acc[i][j] = 0.f;
    #pragma unroll
    for (int h = 0; h < HID; ++h) {
        float a[4], bb[4];
        #pragma unroll
        for (int ii = 0; ii < 4; ++ii) { a[ii] = Z1[ty * 4 + ii][h]; bb[ii] = Z2[tx * 4 + ii][h]; }
        #pragma unroll
        for (int ii = 0; ii < 4; ++ii)
            #pragma unroll
            for (int jj = 0; jj < 4; ++jj)
                acc[ii][jj] += a[ii] * bb[jj];
    }
    #pragma unroll
    for (int ii = 0; ii < 4; ++ii) {
        float* dst = logits + ((size_t)b * NPTS + ti + ty * 4 + ii) * NPTS + tj + tx * 4;
        *(float4*)&dst[0] = *(float4*)&acc[ii][0];
    }
}

// ---------------- K8: row softmax ----------------
__global__ __launch_bounds__(256) void softmax_kernel(const float* __restrict__ logits,
                                                      float* __restrict__ out) {
    int row = blockIdx.x;                         // 0..8191
    const float* L = logits + (size_t)row * NPTS;
    __shared__ float buf[NPTS];
    __shared__ float red[8];
    int tid = threadIdx.x;
    int wave = tid >> 6, lane = tid & 63;
    float mx = -3e38f;
    #pragma unroll
    for (int s = 0; s < 4; ++s) {
        float v = L[tid + s * 256];
        buf[tid + s * 256] = v;
        mx = fmaxf(mx, v);
    }
    #pragma unroll
    for (int off = 32; off > 0; off >>= 1) mx = fmaxf(mx, __shfl_down(mx, off));
    if (lane == 0) red[wave] = mx;
    __syncthreads();
    mx = fmaxf(fmaxf(red[0], red[1]), fmaxf(red[2], red[3]));
    float sum = 0.f;
    #pragma unroll
    for (int s = 0; s < 4; ++s) {
        float e = expf(buf[tid + s * 256] - mx);
        buf[tid + s * 256] = e;
        sum += e;
    }
    #pragma unroll
    for (int off = 32; off > 0; off >>= 1) sum += __shfl_down(sum, off);
    if (lane == 0) red[4 + wave] = sum;
    __syncthreads();
    float inv = 1.f / (red[4] + red[5] + red[6] + red[7]);
    #pragma unroll
    for (int s = 0; s < 4; ++s)
        out[(size_t)row * NPTS + tid + s * 256] = buf[tid + s * 256] * inv;
}

extern "C" void kernel_launch(void* const* d_in, const int* in_sizes, int n_in,
                              void* d_out, int out_size, void* d_ws, size_t ws_size,
                              hipStream_t stream) {
    const float* f1  = (const float*)d_in[0];
    const float* f2  = (const float*)d_in[1];
    const float* W1a = (const float*)d_in[2];
    const float* b1a = (const float*)d_in[3];
    const float* W2a = (const float*)d_in[4];
    const float* b2a = (const float*)d_in[5];
    const float* W1b = (const float*)d_in[6];
    const float* b1b = (const float*)d_in[7];
    const float* W2b = (const float*)d_in[8];
    const float* b2b = (const float*)d_in[9];
    float* out = (float*)d_out;

    // workspace: H packed (100.7MB) | dist (67.1MB, reused as sim logits) | sq | kidx | y | h1 | z
    char* ws = (char*)d_ws;
    unsigned short* H = (unsigned short*)ws;
    float* dist = (float*)(ws + (size_t)NMAT * NPTS * KPACK * sizeof(unsigned short));
    float* sq   = dist + (size_t)NMAT * NPTS * NPTS;
    int*   kidx = (int*)(sq + NMAT * NPTS);
    float* ybuf = (float*)(kidx + NMAT * NPTS * KNN);
    float* h1b  = ybuf + (size_t)NMAT * NPTS * HID;
    float* zb   = h1b + (size_t)NMAT * NPTS * HID;

    split_ymlp_kernel<<<NMAT * NPTS / 64, 512, 0, stream>>>(f1, f2, W1a, H, sq, ybuf);
    gram_mfma_kernel<<<288, 512, 0, stream>>>(H, sq, dist, 0);   // m = 0..7,  1 matrix/XCD
    gram_mfma_kernel<<<288, 512, 0, stream>>>(H, sq, dist, 1);   // m = 8..15, 1 matrix/XCD
    topk_kernel<<<NMAT * NPTS / 4, 256, 0, stream>>>(dist, kidx);
    t1h1_kernel<<<NMAT * NPTS / 64, 512, 0, stream>>>(ybuf, kidx, W2a, b1a, b2a, h1b);
    t2z_kernel<<<NMAT * NPTS / 64, 512, 0, stream>>>(h1b, kidx, W1b, b1b, W2b, b2b, zb);
    sim_kernel<<<BATCH * 256, 256, 0, stream>>>(zb, dist);                      // dist := logits
    softmax_kernel<<<BATCH * NPTS, 256, 0, stream>>>(dist, out);
}

// Round 14
// 480.241 us; speedup vs baseline: 1.1271x; 1.1271x over previous
//
#include <hip/hip_runtime.h>
#include <hip/hip_bf16.h>
#include <math.h>

#define BATCH 8
#define NPTS  1024
#define DIM   1024
#define HID   64
#define KNN   20
#define NMAT  16
#define KPACK 3072   // 3 bf16 segments stored contiguously per row: k = seg*1024 + d

typedef __attribute__((ext_vector_type(8))) short short8;
typedef __attribute__((ext_vector_type(4))) float floatx4;

__device__ __forceinline__ const float* mat_base(const float* f1, const float* f2, int m) {
    return (m < BATCH) ? (f1 + (size_t)m * NPTS * DIM)
                       : (f2 + (size_t)(m - BATCH) * NPTS * DIM);
}

__device__ __forceinline__ unsigned short f2bf_bits(float v) {
    __hip_bfloat16 h = __float2bfloat16(v);   // RNE
    return *(unsigned short*)&h;
}
__device__ __forceinline__ float bfbits2f(unsigned short b) {
    union { unsigned u; float f; } c; c.u = ((unsigned)b) << 16; return c.f;
}

// ---------------- K1: FUSED 3-way bf16 split + squared norms + y = f @ W1a ----------------
// R14: 64-k chunks, 8 elems/thread. Barriers 64 -> 16; H stores widen to 16B/lane
// (short8); loads 2x float4/thread. y: one thread per output, strict ascending k ->
// bitwise identical. H elementwise-identical. sq: partials regroup to 8-col sets
// (reassociation, R1/R10 precedent — absmax held at 0.00390625 both times).
__global__ __launch_bounds__(512) void split_ymlp_kernel(const float* __restrict__ f1,
                                                         const float* __restrict__ f2,
                                                         const float* __restrict__ W,
                                                         unsigned short* __restrict__ H,
                                                         float* __restrict__ sq,
                                                         float* __restrict__ y) {
    int row0 = blockIdx.x * 64;                 // 64-row blocks never straddle matrices
    int m = row0 >> 10;
    const float* A = mat_base(f1, f2, m) + (size_t)(row0 & (NPTS - 1)) * DIM;
    unsigned short* Hb = H + (size_t)row0 * KPACK;
    __shared__ float As[64][72];                // 64 k-cols + 8 pad
    __shared__ float Ws[64][68];                // 64 k-rows x 64 cols + 4 pad
    int tid = threadIdx.x;                      // 0..511
    int r = tid >> 3, c8 = (tid & 7) * 8;       // load map: row r (8 thr/row), cols c8..c8+7
    int ty = tid >> 4, tx = tid & 15;           // GEMM map: rows ty*2..+1, cols tx*4..+3
    float acc[2][4];
    #pragma unroll
    for (int i = 0; i < 2; ++i)
        #pragma unroll
        for (int j = 0; j < 4; ++j) acc[i][j] = 0.f;
    float sqp = 0.f;
    unsigned short* Hr = Hb + (size_t)r * KPACK + c8;

    for (int kk = 0; kk < DIM; kk += 64) {
        float4 a0 = *(const float4*)&A[(size_t)r * DIM + kk + c8];
        float4 a1 = *(const float4*)&A[(size_t)r * DIM + kk + c8 + 4];
        // ---- split (bitwise-identical elementwise chain), 8 elems ----
        {
            float vv[8] = {a0.x, a0.y, a0.z, a0.w, a1.x, a1.y, a1.z, a1.w};
            short8 h1, h2, h3;
            #pragma unroll
            for (int c = 0; c < 8; ++c) {
                unsigned short b1 = f2bf_bits(vv[c]);
                float r1 = vv[c] - bfbits2f(b1);
                unsigned short b2 = f2bf_bits(r1);
                float r2 = r1 - bfbits2f(b2);
                unsigned short b3 = f2bf_bits(r2);
                h1[c] = (short)b1; h2[c] = (short)b2; h3[c] = (short)b3;
                sqp += vv[c] * vv[c];
            }
            *(short8*)&Hr[kk]        = h1;
            *(short8*)&Hr[1024 + kk] = h2;
            *(short8*)&Hr[2048 + kk] = h3;
        }
        // ---- GEMM staging ----
        *(float4*)&As[r][c8]     = a0;
        *(float4*)&As[r][c8 + 4] = a1;
        {
            int d = tid >> 3, hh = (tid & 7) * 8;    // 64 k-rows x 8 col-groups
            *(float4*)&Ws[d][hh]     = *(const float4*)&W[(size_t)(kk + d) * HID + hh];
            *(float4*)&Ws[d][hh + 4] = *(const float4*)&W[(size_t)(kk + d) * HID + hh + 4];
        }
        __syncthreads();
        #pragma unroll
        for (int k = 0; k < 64; ++k) {
            float av[2];
            #pragma unroll
            for (int ii = 0; ii < 2; ++ii) av[ii] = As[ty * 2 + ii][k];
            float4 w = *(const float4*)&Ws[k][tx * 4];
            #pragma unroll
            for (int ii = 0; ii < 2; ++ii) {
                acc[ii][0] += av[ii] * w.x;
                acc[ii][1] += av[ii] * w.y;
                acc[ii][2] += av[ii] * w.z;
                acc[ii][3] += av[ii] * w.w;
            }
        }
        __syncthreads();
    }
    // sq: combine the 8 per-thread partials of each row (lanes 8r..8r+7 contiguous)
    sqp += __shfl_down(sqp, 4);
    sqp += __shfl_down(sqp, 2);
    sqp += __shfl_down(sqp, 1);
    if ((tid & 7) == 0) sq[row0 + r] = sqp;
    #pragma unroll
    for (int ii = 0; ii < 2; ++ii)
        *(float4*)&y[(size_t)(row0 + ty * 2 + ii) * HID + tx * 4] = *(float4*)&acc[ii][0];
}

// ---------------- K2: Gram -> squared distances via bf16 MFMA ----------------
// R14: EXACT R12 REVERT (proven 185.4us @ 483.3 total). Gram is CLOSED: R3 (depth),
// R10/R11 (occupancy), R4/R9 (tiles), R5/R13 (residency) all measured. R13's lesson:
// the ~5 TB/s staged throughput is built from per-CU request concurrency (2 blocks x
// 8 waves x 12 counted loads); halving co-resident blocks dropped per-block rate
// 16->12.4 GB/s despite BETTER cache locality (FETCH 95->62MB). Max co-residency at
// min bytes = this config. Single 576-block launch, 512 threads, triple-buffered B,
// vmcnt(12) counted pipeline, R9 prologue drain. Bounds-3 forbidden (R6 flake).
#define GRAM_STEP(CURAF, NXTAF, CBUF, NBUF, KN, ISSUE, WAITOP)                             \
  {                                                                                        \
    if (ISSUE) {                                                                           \
      _Pragma("unroll")                                                                    \
      for (int s = 0; s < 3; ++s)                                                          \
        NXTAF[s] = *(const short8*)&Hm[(size_t)(ti + (w << 4) + r16) * KPACK               \
                                       + (size_t)(s << 10) + (KN) + (kc << 3)];            \
      _Pragma("unroll")                                                                    \
      for (int c = 0; c < 3; ++c) {                                                        \
        int ca = w * 3 + c; int seg = ca >> 3; int rb = ca & 7;                            \
        const unsigned short* gb = Hm + (size_t)(tj + rb * 16 + r16) * KPACK               \
                                      + (size_t)(seg << 10) + (KN) + (kc << 3);            \
        __builtin_amdgcn_global_load_lds(                                                  \
            (const __attribute__((address_space(1))) void*)gb,                             \
            (__attribute__((address_space(3))) void*)&Bsl[NBUF][ca * 512], 16, 0, 0);      \
      }                                                                                    \
    }                                                                                      \
    asm volatile(WAITOP ::: "memory");                                                     \
    __builtin_amdgcn_s_barrier();                                                          \
    asm volatile("" ::: "memory");                                                         \
    __builtin_amdgcn_s_setprio(1);                                                         \
    _Pragma("unroll")                                                                      \
    for (int sb = 0; sb < 3; ++sb) {                                                       \
      short8 bf[8];                                                                        \
      _Pragma("unroll")                                                                    \
      for (int b = 0; b < 8; ++b)                                                          \
        bf[b] = *(const short8*)&Bsl[CBUF][(sb * 8 + b) * 512 + lane * 8];                 \
      _Pragma("unroll")                                                                    \
      for (int sa = 0; sa < 3; ++sa) {                                                     \
        if (sa + sb > 2) continue;                                                         \
        _Pragma("unroll")                                                                  \
        for (int b = 0; b < 8; ++b)                                                        \
          acc[b] = __builtin_amdgcn_mfma_f32_16x16x32_bf16(CURAF[sa], bf[b],               \
                                                           acc[b], 0, 0, 0);               \
      }                                                                                    \
    }                                                                                      \
    __builtin_amdgcn_s_setprio(0);                                                         \
    asm volatile("" ::: "memory");                                                         \
    __builtin_amdgcn_s_barrier();                                                          \
  }

__global__ __launch_bounds__(512, 4) void gram_mfma_kernel(const unsigned short* __restrict__ H,
                                                           const float* __restrict__ sq,
                                                           float* __restrict__ dist) {
    int bid = blockIdx.x;
    int xcd = bid & 7;
    int g = bid >> 3;                 // 0..71
    int m = xcd + 8 * (g & 1);        // interleave this XCD's two matrices
    int t = g >> 1;                   // 0..35
    int bi = 0;
    { int a = t; while (a >= 8 - bi) { a -= 8 - bi; ++bi; } t = a; }
    int bj = bi + t;
    int ti = bi << 7, tj = bj << 7;

    const unsigned short* Hm = H + (size_t)m * NPTS * KPACK;

    // B chunks: ca = seg*8 + colblk ; each chunk: [lane(64)][8 shorts] = 1KB (16 cols x 32 k)
    __shared__ __align__(16) unsigned short Bsl[3][24 * 512];   // 3 x 24 KB triple buffer

    int tid = threadIdx.x;
    int w = tid >> 6, lane = tid & 63;   // 8 waves; wave owns rows ti + w*16 .. +15
    int r16 = lane & 15, kc = lane >> 4;

    floatx4 acc[8];
    #pragma unroll
    for (int b = 0; b < 8; ++b) acc[b] = (floatx4)0.f;

    // A fragment triple buffers: wave-private rows (3 segs x 1 rowblock each)
    short8 afA[3], afB[3], afC[3];

    // ---- prologue (grouped: afA | B0-DMA | afB | B1-DMA, then full drain) ----
    #pragma unroll
    for (int s = 0; s < 3; ++s)
        afA[s] = *(const short8*)&Hm[(size_t)(ti + (w << 4) + r16) * KPACK
                                     + (size_t)(s << 10) + (kc << 3)];
    asm volatile("" ::: "memory");
    #pragma unroll
    for (int c = 0; c < 3; ++c) {
        int ca = w * 3 + c; int seg = ca >> 3; int rb = ca & 7;
        const unsigned short* gb = Hm + (size_t)(tj + rb * 16 + r16) * KPACK
                                      + (size_t)(seg << 10) + (kc << 3);
        __builtin_amdgcn_global_load_lds(
            (const __attribute__((address_space(1))) void*)gb,
            (__attribute__((address_space(3))) void*)&Bsl[0][ca * 512], 16, 0, 0);
    }
    asm volatile("" ::: "memory");
    #pragma unroll
    for (int s = 0; s < 3; ++s)
        afB[s] = *(const short8*)&Hm[(size_t)(ti + (w << 4) + r16) * KPACK
                                     + (size_t)(s << 10) + 32 + (kc << 3)];
    asm volatile("" ::: "memory");
    #pragma unroll
    for (int c = 0; c < 3; ++c) {
        int ca = w * 3 + c; int seg = ca >> 3; int rb = ca & 7;
        const unsigned short* gb = Hm + (size_t)(tj + rb * 16 + r16) * KPACK
                                      + (size_t)(seg << 10) + 32 + (kc << 3);
        __builtin_amdgcn_global_load_lds(
            (const __attribute__((address_space(1))) void*)gb,
            (__attribute__((address_space(3))) void*)&Bsl[1][ca * 512], 16, 0, 0);
    }
    // Full drain: slices 0/1 complete before the loop; steps 0/1's vmcnt(12) are
    // no-ops (6/12 outstanding); steady state from step 2 retires exactly one slice.
    asm volatile("s_waitcnt vmcnt(0)" ::: "memory");

    // slices 0..29: compute t, issue t+2, wait vmcnt(12) (t+1,t+2 in flight: 6+6)
    #pragma unroll 1
    for (int t2 = 0; t2 < 30; t2 += 3) {
        GRAM_STEP(afA, afC, 0, 2, (t2 + 2) * 32, 1, "s_waitcnt vmcnt(12)");
        GRAM_STEP(afB, afA, 1, 0, (t2 + 3) * 32, 1, "s_waitcnt vmcnt(12)");
        GRAM_STEP(afC, afB, 2, 1, (t2 + 4) * 32, 1, "s_waitcnt vmcnt(12)");
    }
    // epilogue: slice 30 (slice 31 still in flight), then slice 31
    GRAM_STEP(afA, afC, 0, 2, 0, 0, "s_waitcnt vmcnt(6)");
    GRAM_STEP(afB, afC, 1, 2, 0, 0, "s_waitcnt vmcnt(0)");

    const float* sqm = sq + m * NPTS;
    {
        int i0 = ti + (w << 4) + (lane >> 4) * 4;
        #pragma unroll
        for (int b = 0; b < 8; ++b) {
            int j = tj + b * 16 + (lane & 15);
            float sqj = sqm[j];
            #pragma unroll
            for (int r = 0; r < 4; ++r) {
                int i = i0 + r;
                float v = sqm[i] + sqj - 2.f * acc[b][r];
                if (i == j) v += 1e10f;
                dist[((size_t)m * NPTS + i) * NPTS + j] = v;
                if (bi != bj) dist[((size_t)m * NPTS + j) * NPTS + i] = v;
            }
        }
    }
}

// ---------------- K3: top-k (k=20 smallest), one wave per row, all-register ----------------
__global__ __launch_bounds__(256) void topk_kernel(const float* __restrict__ dist,
                                                   int* __restrict__ knn_idx) {
    int tid = threadIdx.x;
    int wave = tid >> 6, lane = tid & 63;
    int row = blockIdx.x * 4 + wave;
    const float* d = dist + (size_t)row * NPTS;
    float v[16];
    #pragma unroll
    for (int s = 0; s < 16; ++s) v[s] = d[s * 64 + lane];
    int myj = 0;
    for (int sel = 0; sel < KNN; ++sel) {
        float bv = v[0]; int bs = 0;
        #pragma unroll
        for (int s = 1; s < 16; ++s)
            if (v[s] < bv) { bv = v[s]; bs = s; }   // ascending s: lowest j locally on ties
        int bj = bs * 64 + lane;
        #pragma unroll
        for (int off = 1; off < 64; off <<= 1) {
            float ov = __shfl_xor(bv, off);
            int   oj = __shfl_xor(bj, off);
            if (ov < bv || (ov == bv && oj < bj)) { bv = ov; bj = oj; }
        }
        if ((bj & 63) == lane) v[bj >> 6] = 3e38f;  // owner clears
        if (lane == sel) myj = bj;
    }
    if (lane < KNN) knn_idx[(size_t)row * KNN + lane] = myj;
}

// ---------------- K5: t1 = relu(y_i + sum y_n + b1a); h1 = t1 @ W2a + b2a ----------------
// R12 version (proven): 512 threads, 8 waves/CU.
__global__ __launch_bounds__(512) void t1h1_kernel(const float* __restrict__ y,
                                                   const int* __restrict__ knn_idx,
                                                   const float* __restrict__ W,
                                                   const float* __restrict__ bias1,
                                                   const float* __restrict__ bias2,
                                                   float* __restrict__ h1) {
    int row0 = blockIdx.x * 64;
    int m = row0 >> 10;
    __shared__ int nb[64 * KNN];
    __shared__ float t1s[64][65];
    __shared__ float Ws[64][HID];
    __shared__ float b1s[HID], b2s[HID];
    int tid = threadIdx.x;                       // 0..511
    for (int k = tid; k < 64 * KNN; k += 512) nb[k] = knn_idx[(size_t)row0 * KNN + k];
    for (int k = tid; k < 64 * HID; k += 512) Ws[k >> 6][k & 63] = W[k];
    if (tid < HID) { b1s[tid] = bias1[tid]; b2s[tid] = bias2[tid]; }
    __syncthreads();
    {
        int r = tid >> 3, c0 = (tid & 7) * 8;    // 8 threads/row, 8 cols each
        const float* yr = y + (size_t)(row0 + r) * HID + c0;
        float4 a[2];
        #pragma unroll
        for (int q = 0; q < 2; ++q) a[q] = *(const float4*)&yr[q * 4];
        const float* ym = y + (size_t)(m << 10) * HID;
        #pragma unroll
        for (int t = 0; t < KNN; ++t) {
            const float* yn = ym + (size_t)nb[r * KNN + t] * HID + c0;
            #pragma unroll
            for (int q = 0; q < 2; ++q) {
                float4 v = *(const float4*)&yn[q * 4];
                a[q].x += v.x; a[q].y += v.y; a[q].z += v.z; a[q].w += v.w;
            }
        }
        #pragma unroll
        for (int q = 0; q < 2; ++q) {
            int c = c0 + q * 4;
            t1s[r][c + 0] = fmaxf(a[q].x + b1s[c + 0], 0.f);
            t1s[r][c + 1] = fmaxf(a[q].y + b1s[c + 1], 0.f);
            t1s[r][c + 2] = fmaxf(a[q].z + b1s[c + 2], 0.f);
            t1s[r][c + 3] = fmaxf(a[q].w + b1s[c + 3], 0.f);
        }
    }
    __syncthreads();
    int ty = tid >> 4, tx = tid & 15;            // rows ty*2..+1, cols tx*4..+3
    float acc[2][4];
    #pragma unroll
    for (int i = 0; i < 2; ++i)
        #pragma unroll
        for (int j = 0; j < 4; ++j) acc[i][j] = 0.f;
    #pragma unroll
    for (int k = 0; k < HID; ++k) {
        float a[2];
        #pragma unroll
        for (int ii = 0; ii < 2; ++ii) a[ii] = t1s[ty * 2 + ii][k];
        float4 w = *(const float4*)&Ws[k][tx * 4];
        #pragma unroll
        for (int ii = 0; ii < 2; ++ii) {
            acc[ii][0] += a[ii] * w.x;
            acc[ii][1] += a[ii] * w.y;
            acc[ii][2] += a[ii] * w.z;
            acc[ii][3] += a[ii] * w.w;
        }
    }
    #pragma unroll
    for (int ii = 0; ii < 2; ++ii) {
        float o[4];
        #pragma unroll
        for (int jj = 0; jj < 4; ++jj) o[jj] = acc[ii][jj] + b2s[tx * 4 + jj];
        *(float4*)&h1[(size_t)(row0 + ty * 2 + ii) * HID + tx * 4] = *(float4*)&o[0];
    }
}

// ---------------- K6: hs = h1_i + sum h1_n; t2 = relu(hs@W1b+b1b); z = t2@W2b+b2b ----------------
// R12 version (proven): 512 threads, 8 waves/CU.
__global__ __launch_bounds__(512) void t2z_kernel(const float* __restrict__ h1,
                                                  const int* __restrict__ knn_idx,
                                                  const float* __restrict__ W1,
                                                  const float* __restrict__ bias1,
                                                  const float* __restrict__ W2,
                                                  const float* __restrict__ bias2,
                                                  float* __restrict__ z) {
    int row0 = blockIdx.x * 64;
    int m = row0 >> 10;
    __shared__ int nb[64 * KNN];
    __shared__ float hs[64][65];
    __shared__ float t2s[64][65];
    __shared__ float Ws[64][HID];
    __shared__ float b1s[HID], b2s[HID];
    int tid = threadIdx.x;                       // 0..511
    for (int k = tid; k < 64 * KNN; k += 512) nb[k] = knn_idx[(size_t)row0 * KNN + k];
    for (int k = tid; k < 64 * HID; k += 512) Ws[k >> 6][k & 63] = W1[k];
    if (tid < HID) { b1s[tid] = bias1[tid]; b2s[tid] = bias2[tid]; }
    __syncthreads();
    {
        int r = tid >> 3, c0 = (tid & 7) * 8;
        const float* hr = h1 + (size_t)(row0 + r) * HID + c0;
        float4 a[2];
        #pragma unroll
        for (int q = 0; q < 2; ++q) a[q] = *(const float4*)&hr[q * 4];
        const float* hm = h1 + (size_t)(m << 10) * HID;
        #pragma unroll
        for (int t = 0; t < KNN; ++t) {
            const float* hn = hm + (size_t)nb[r * KNN + t] * HID + c0;
            #pragma unroll
            for (int q = 0; q < 2; ++q) {
                float4 v = *(const float4*)&hn[q * 4];
                a[q].x += v.x; a[q].y += v.y; a[q].z += v.z; a[q].w += v.w;
            }
        }
        #pragma unroll
        for (int q = 0; q < 2; ++q) *(float4*)&hs[r][c0 + q * 4] = a[q];
    }
    __syncthreads();
    int ty = tid >> 4, tx = tid & 15;
    float acc[2][4];
    #pragma unroll
    for (int i = 0; i < 2; ++i)
        #pragma unroll
        for (int j = 0; j < 4; ++j) acc[i][j] = 0.f;
    #pragma unroll
    for (int k = 0; k < HID; ++k) {
        float a[2];
        #pragma unroll
        for (int ii = 0; ii < 2; ++ii) a[ii] = hs[ty * 2 + ii][k];
        float4 w = *(const float4*)&Ws[k][tx * 4];
        #pragma unroll
        for (int ii = 0; ii < 2; ++ii) {
            acc[ii][0] += a[ii] * w.x;
            acc[ii][1] += a[ii] * w.y;
            acc[ii][2] += a[ii] * w.z;
            acc[ii][3] += a[ii] * w.w;
        }
    }
    #pragma unroll
    for (int ii = 0; ii < 2; ++ii)
        #pragma unroll
        for (int jj = 0; jj < 4; ++jj)
            t2s[ty * 2 + ii][tx * 4 + jj] = fmaxf(acc[ii][jj] + b1s[tx * 4 + jj], 0.f);
    __syncthreads();
    for (int k = tid; k < 64 * HID; k += 512) Ws[k >> 6][k & 63] = W2[k];
    __syncthreads();
    #pragma unroll
    for (int i = 0; i < 2; ++i)
        #pragma unroll
        for (int j = 0; j < 4; ++j) acc[i][j] = 0.f;
    #pragma unroll
    for (int k = 0; k < HID; ++k) {
        float a[2];
        #pragma unroll
        for (int ii = 0; ii < 2; ++ii) a[ii] = t2s[ty * 2 + ii][k];
        float4 w = *(const float4*)&Ws[k][tx * 4];
        #pragma unroll
        for (int ii = 0; ii < 2; ++ii) {
            acc[ii][0] += a[ii] * w.x;
            acc[ii][1] += a[ii] * w.y;
            acc[ii][2] += a[ii] * w.z;
            acc[ii][3] += a[ii] * w.w;
        }
    }
    #pragma unroll
    for (int ii = 0; ii < 2; ++ii) {
        float o[4];
        #pragma unroll
        for (int jj = 0; jj < 4; ++jj) o[jj] = acc[ii][jj] + b2s[tx * 4 + jj];
        *(float4*)&z[(size_t)(row0 + ty * 2 + ii) * HID + tx * 4] = *(float4*)&o[0];
    }
}

// ---------------- K7: sim = z1 @ z2^T (64x64 tiles, K=64) ----------------
__global__ __launch_bounds__(256) void sim_kernel(const float* __restrict__ z,
                                                  float* __restrict__ logits) {
    int bid = blockIdx.x;
    int b = bid >> 8;
    int tile = bid & 255;
    int ti = (tile >> 4) << 6;
    int tj = (tile & 15) << 6;
    const float* z1 = z + (size_t)b * NPTS * HID;
    const float* z2 = z + (size_t)(BATCH + b) * NPTS * HID;
    __shared__ float Z1[64][68];
    __shared__ float Z2[64][68];
    int tid = threadIdx.x;
    #pragma unroll
    for (int i = 0; i < 4; ++i) {
        int l = tid + i * 256;
        int r = l >> 4, c = (l & 15) * 4;
        *(float4*)&Z1[r][c] = *(const float4*)&z1[(size_t)(ti + r) * HID + c];
        *(float4*)&Z2[r][c] = *(const float4*)&z2[(size_t)(tj + r) * HID + c];
    }
    __syncthreads();
    int ty = tid >> 4, tx = tid & 15;
    float acc[4][4];
    #pragma unroll
    for (int i = 0; i < 4; ++i)
        #pragma unroll
        for (int j = 0; j < 4; ++j) acc[i][j] = 0.f;
    #pragma unroll
    for (int h = 0; h < HID; ++h) {
        float a[4], bb[4];
        #pragma unroll
        for (int ii = 0; ii < 4; ++ii) { a[ii] = Z1[ty * 4 + ii][h]; bb[ii] = Z2[tx * 4 + ii][h]; }
        #pragma unroll
        for (int ii = 0; ii < 4; ++ii)
            #pragma unroll
            for (int jj = 0; jj < 4; ++jj)
                acc[ii][jj] += a[ii] * bb[jj];
    }
    #pragma unroll
    for (int ii = 0; ii < 4; ++ii) {
        float* dst = logits + ((size_t)b * NPTS + ti + ty * 4 + ii) * NPTS + tj + tx * 4;
        *(float4*)&dst[0] = *(float4*)&acc[ii][0];
    }
}

// ---------------- K8: row softmax ----------------
__global__ __launch_bounds__(256) void softmax_kernel(const float* __restrict__ logits,
                                                      float* __restrict__ out) {
    int row = blockIdx.x;                         // 0..8191
    const float* L = logits + (size_t)row * NPTS;
    __shared__ float buf[NPTS];
    __shared__ float red[8];
    int tid = threadIdx.x;
    int wave = tid >> 6, lane = tid & 63;
    float mx = -3e38f;
    #pragma unroll
    for (int s = 0; s < 4; ++s) {
        float v = L[tid + s * 256];
        buf[tid + s * 256] = v;
        mx = fmaxf(mx, v);
    }
    #pragma unroll
    for (int off = 32; off > 0; off >>= 1) mx = fmaxf(mx, __shfl_down(mx, off));
    if (lane == 0) red[wave] = mx;
    __syncthreads();
    mx = fmaxf(fmaxf(red[0], red[1]), fmaxf(red[2], red[3]));
    float sum = 0.f;
    #pragma unroll
    for (int s = 0; s < 4; ++s) {
        float e = expf(buf[tid + s * 256] - mx);
        buf[tid + s * 256] = e;
        sum += e;
    }
    #pragma unroll
    for (int off = 32; off > 0; off >>= 1) sum += __shfl_down(sum, off);
    if (lane == 0) red[4 + wave] = sum;
    __syncthreads();
    float inv = 1.f / (red[4] + red[5] + red[6] + red[7]);
    #pragma unroll
    for (int s = 0; s < 4; ++s)
        out[(size_t)row * NPTS + tid + s * 256] = buf[tid + s * 256] * inv;
}

extern "C" void kernel_launch(void* const* d_in, const int* in_sizes, int n_in,
                              void* d_out, int out_size, void* d_ws, size_t ws_size,
                              hipStream_t stream) {
    const float* f1  = (const float*)d_in[0];
    const float* f2  = (const float*)d_in[1];
    const float* W1a = (const float*)d_in[2];
    const float* b1a = (const float*)d_in[3];
    const float* W2a = (const float*)d_in[4];
    const float* b2a = (const float*)d_in[5];
    const float* W1b = (const float*)d_in[6];
    const float* b1b = (const float*)d_in[7];
    const float* W2b = (const float*)d_in[8];
    const float* b2b = (const float*)d_in[9];
    float* out = (float*)d_out;

    // workspace: H packed (100.7MB) | dist (67.1MB, reused as sim logits) | sq | kidx | y | h1 | z
    char* ws = (char*)d_ws;
    unsigned short* H = (unsigned short*)ws;
    float* dist = (float*)(ws + (size_t)NMAT * NPTS * KPACK * sizeof(unsigned short));
    float* sq   = dist + (size_t)NMAT * NPTS * NPTS;
    int*   kidx = (int*)(sq + NMAT * NPTS);
    float* ybuf = (float*)(kidx + NMAT * NPTS * KNN);
    float* h1b  = ybuf + (size_t)NMAT * NPTS * HID;
    float* zb   = h1b + (size_t)NMAT * NPTS * HID;

    split_ymlp_kernel<<<NMAT * NPTS / 64, 512, 0, stream>>>(f1, f2, W1a, H, sq, ybuf);
    gram_mfma_kernel<<<NMAT * 36, 512, 0, stream>>>(H, sq, dist);
    topk_kernel<<<NMAT * NPTS / 4, 256, 0, stream>>>(dist, kidx);
    t1h1_kernel<<<NMAT * NPTS / 64, 512, 0, stream>>>(ybuf, kidx, W2a, b1a, b2a, h1b);
    t2z_kernel<<<NMAT * NPTS / 64, 512, 0, stream>>>(h1b, kidx, W1b, b1b, W2b, b2b, zb);
    sim_kernel<<<BATCH * 256, 256, 0, stream>>>(zb, dist);                      // dist := logits
    softmax_kernel<<<BATCH * NPTS, 256, 0, stream>>>(dist, out);
}

// Round 16
// 476.879 us; speedup vs baseline: 1.1350x; 1.0070x over previous
//
#include <hip/hip_runtime.h>
#include <hip/hip_bf16.h>
#include <math.h>

#define BATCH 8
#define NPTS  1024
#define DIM   1024
#define HID   64
#define KNN   20
#define NMAT  16
#define KPACK 3072   // 3 bf16 segments stored contiguously per row: k = seg*1024 + d

typedef __attribute__((ext_vector_type(8))) short short8;
typedef __attribute__((ext_vector_type(4))) float floatx4;

__device__ __forceinline__ const float* mat_base(const float* f1, const float* f2, int m) {
    return (m < BATCH) ? (f1 + (size_t)m * NPTS * DIM)
                       : (f2 + (size_t)(m - BATCH) * NPTS * DIM);
}

__device__ __forceinline__ unsigned short f2bf_bits(float v) {
    __hip_bfloat16 h = __float2bfloat16(v);   // RNE
    return *(unsigned short*)&h;
}
__device__ __forceinline__ float bfbits2f(unsigned short b) {
    union { unsigned u; float f; } c; c.u = ((unsigned)b) << 16; return c.f;
}

// ---------------- K1: FUSED 3-way bf16 split + squared norms + y = f @ W1a ----------------
// R14 version (best verified). R15 lesson: the 3-seg split (error ~2^-26) is the MINIMUM
// precision that keeps topk stable — 2-seg (~1e-3 dist error) flipped neighbor sets en
// masse (absmax 0.83). Do not reduce split precision.
__global__ __launch_bounds__(512) void split_ymlp_kernel(const float* __restrict__ f1,
                                                         const float* __restrict__ f2,
                                                         const float* __restrict__ W,
                                                         unsigned short* __restrict__ H,
                                                         float* __restrict__ sq,
                                                         float* __restrict__ y) {
    int row0 = blockIdx.x * 64;                 // 64-row blocks never straddle matrices
    int m = row0 >> 10;
    const float* A = mat_base(f1, f2, m) + (size_t)(row0 & (NPTS - 1)) * DIM;
    unsigned short* Hb = H + (size_t)row0 * KPACK;
    __shared__ float As[64][72];                // 64 k-cols + 8 pad
    __shared__ float Ws[64][68];                // 64 k-rows x 64 cols + 4 pad
    int tid = threadIdx.x;                      // 0..511
    int r = tid >> 3, c8 = (tid & 7) * 8;       // load map: row r (8 thr/row), cols c8..c8+7
    int ty = tid >> 4, tx = tid & 15;           // GEMM map: rows ty*2..+1, cols tx*4..+3
    float acc[2][4];
    #pragma unroll
    for (int i = 0; i < 2; ++i)
        #pragma unroll
        for (int j = 0; j < 4; ++j) acc[i][j] = 0.f;
    float sqp = 0.f;
    unsigned short* Hr = Hb + (size_t)r * KPACK + c8;

    for (int kk = 0; kk < DIM; kk += 64) {
        float4 a0 = *(const float4*)&A[(size_t)r * DIM + kk + c8];
        float4 a1 = *(const float4*)&A[(size_t)r * DIM + kk + c8 + 4];
        // ---- split (bitwise-identical elementwise chain), 8 elems ----
        {
            float vv[8] = {a0.x, a0.y, a0.z, a0.w, a1.x, a1.y, a1.z, a1.w};
            short8 h1, h2, h3;
            #pragma unroll
            for (int c = 0; c < 8; ++c) {
                unsigned short b1 = f2bf_bits(vv[c]);
                float r1 = vv[c] - bfbits2f(b1);
                unsigned short b2 = f2bf_bits(r1);
                float r2 = r1 - bfbits2f(b2);
                unsigned short b3 = f2bf_bits(r2);
                h1[c] = (short)b1; h2[c] = (short)b2; h3[c] = (short)b3;
                sqp += vv[c] * vv[c];
            }
            *(short8*)&Hr[kk]        = h1;
            *(short8*)&Hr[1024 + kk] = h2;
            *(short8*)&Hr[2048 + kk] = h3;
        }
        // ---- GEMM staging ----
        *(float4*)&As[r][c8]     = a0;
        *(float4*)&As[r][c8 + 4] = a1;
        {
            int d = tid >> 3, hh = (tid & 7) * 8;    // 64 k-rows x 8 col-groups
            *(float4*)&Ws[d][hh]     = *(const float4*)&W[(size_t)(kk + d) * HID + hh];
            *(float4*)&Ws[d][hh + 4] = *(const float4*)&W[(size_t)(kk + d) * HID + hh + 4];
        }
        __syncthreads();
        #pragma unroll
        for (int k = 0; k < 64; ++k) {
            float av[2];
            #pragma unroll
            for (int ii = 0; ii < 2; ++ii) av[ii] = As[ty * 2 + ii][k];
            float4 w = *(const float4*)&Ws[k][tx * 4];
            #pragma unroll
            for (int ii = 0; ii < 2; ++ii) {
                acc[ii][0] += av[ii] * w.x;
                acc[ii][1] += av[ii] * w.y;
                acc[ii][2] += av[ii] * w.z;
                acc[ii][3] += av[ii] * w.w;
            }
        }
        __syncthreads();
    }
    // sq: combine the 8 per-thread partials of each row (lanes 8r..8r+7 contiguous)
    sqp += __shfl_down(sqp, 4);
    sqp += __shfl_down(sqp, 2);
    sqp += __shfl_down(sqp, 1);
    if ((tid & 7) == 0) sq[row0 + r] = sqp;
    #pragma unroll
    for (int ii = 0; ii < 2; ++ii)
        *(float4*)&y[(size_t)(row0 + ty * 2 + ii) * HID + tx * 4] = *(float4*)&acc[ii][0];
}

// ---------------- K2: Gram -> squared distances via bf16 MFMA ----------------
// R14 version (best verified, 186us). Gram is CLOSED — all axes measured: depth (R3),
// occupancy (R10/R11), tiling (R4/R8/R9), residency (R5/R13), scheduling (R1/R2),
// precision (R15: 2-seg FAILED, absmax 0.83 — topk gaps << 1e-3). 905MB staged stream
// at concurrency-built ~5 TB/s is the floor. Single 576-block launch, 512 threads,
// triple-buffered B, vmcnt(12) counted pipeline, R9 prologue drain. Bounds-3 forbidden.
#define GRAM_STEP(CURAF, NXTAF, CBUF, NBUF, KN, ISSUE, WAITOP)                             \
  {                                                                                        \
    if (ISSUE) {                                                                           \
      _Pragma("unroll")                                                                    \
      for (int s = 0; s < 3; ++s)                                                          \
        NXTAF[s] = *(const short8*)&Hm[(size_t)(ti + (w << 4) + r16) * KPACK               \
                                       + (size_t)(s << 10) + (KN) + (kc << 3)];            \
      _Pragma("unroll")                                                                    \
      for (int c = 0; c < 3; ++c) {                                                        \
        int ca = w * 3 + c; int seg = ca >> 3; int rb = ca & 7;                            \
        const unsigned short* gb = Hm + (size_t)(tj + rb * 16 + r16) * KPACK               \
                                      + (size_t)(seg << 10) + (KN) + (kc << 3);            \
        __builtin_amdgcn_global_load_lds(                                                  \
            (const __attribute__((address_space(1))) void*)gb,                             \
            (__attribute__((address_space(3))) void*)&Bsl[NBUF][ca * 512], 16, 0, 0);      \
      }                                                                                    \
    }                                                                                      \
    asm volatile(WAITOP ::: "memory");                                                     \
    __builtin_amdgcn_s_barrier();                                                          \
    asm volatile("" ::: "memory");                                                         \
    __builtin_amdgcn_s_setprio(1);                                                         \
    _Pragma("unroll")                                                                      \
    for (int sb = 0; sb < 3; ++sb) {                                                       \
      short8 bf[8];                                                                        \
      _Pragma("unroll")                                                                    \
      for (int b = 0; b < 8; ++b)                                                          \
        bf[b] = *(const short8*)&Bsl[CBUF][(sb * 8 + b) * 512 + lane * 8];                 \
      _Pragma("unroll")                                                                    \
      for (int sa = 0; sa < 3; ++sa) {                                                     \
        if (sa + sb > 2) continue;                                                         \
        _Pragma("unroll")                                                                  \
        for (int b = 0; b < 8; ++b)                                                        \
          acc[b] = __builtin_amdgcn_mfma_f32_16x16x32_bf16(CURAF[sa], bf[b],               \
                                                           acc[b], 0, 0, 0);               \
      }                                                                                    \
    }                                                                                      \
    __builtin_amdgcn_s_setprio(0);                                                         \
    asm volatile("" ::: "memory");                                                         \
    __builtin_amdgcn_s_barrier();                                                          \
  }

__global__ __launch_bounds__(512, 4) void gram_mfma_kernel(const unsigned short* __restrict__ H,
                                                           const float* __restrict__ sq,
                                                           float* __restrict__ dist) {
    int bid = blockIdx.x;
    int xcd = bid & 7;
    int g = bid >> 3;                 // 0..71
    int m = xcd + 8 * (g & 1);        // interleave this XCD's two matrices
    int t = g >> 1;                   // 0..35
    int bi = 0;
    { int a = t; while (a >= 8 - bi) { a -= 8 - bi; ++bi; } t = a; }
    int bj = bi + t;
    int ti = bi << 7, tj = bj << 7;

    const unsigned short* Hm = H + (size_t)m * NPTS * KPACK;

    // B chunks: ca = seg*8 + colblk ; each chunk: [lane(64)][8 shorts] = 1KB (16 cols x 32 k)
    __shared__ __align__(16) unsigned short Bsl[3][24 * 512];   // 3 x 24 KB triple buffer

    int tid = threadIdx.x;
    int w = tid >> 6, lane = tid & 63;   // 8 waves; wave owns rows ti + w*16 .. +15
    int r16 = lane & 15, kc = lane >> 4;

    floatx4 acc[8];
    #pragma unroll
    for (int b = 0; b < 8; ++b) acc[b] = (floatx4)0.f;

    // A fragment triple buffers: wave-private rows (3 segs x 1 rowblock each)
    short8 afA[3], afB[3], afC[3];

    // ---- prologue (grouped: afA | B0-DMA | afB | B1-DMA, then full drain) ----
    #pragma unroll
    for (int s = 0; s < 3; ++s)
        afA[s] = *(const short8*)&Hm[(size_t)(ti + (w << 4) + r16) * KPACK
                                     + (size_t)(s << 10) + (kc << 3)];
    asm volatile("" ::: "memory");
    #pragma unroll
    for (int c = 0; c < 3; ++c) {
        int ca = w * 3 + c; int seg = ca >> 3; int rb = ca & 7;
        const unsigned short* gb = Hm + (size_t)(tj + rb * 16 + r16) * KPACK
                                      + (size_t)(seg << 10) + (kc << 3);
        __builtin_amdgcn_global_load_lds(
            (const __attribute__((address_space(1))) void*)gb,
            (__attribute__((address_space(3))) void*)&Bsl[0][ca * 512], 16, 0, 0);
    }
    asm volatile("" ::: "memory");
    #pragma unroll
    for (int s = 0; s < 3; ++s)
        afB[s] = *(const short8*)&Hm[(size_t)(ti + (w << 4) + r16) * KPACK
                                     + (size_t)(s << 10) + 32 + (kc << 3)];
    asm volatile("" ::: "memory");
    #pragma unroll
    for (int c = 0; c < 3; ++c) {
        int ca = w * 3 + c; int seg = ca >> 3; int rb = ca & 7;
        const unsigned short* gb = Hm + (size_t)(tj + rb * 16 + r16) * KPACK
                                      + (size_t)(seg << 10) + 32 + (kc << 3);
        __builtin_amdgcn_global_load_lds(
            (const __attribute__((address_space(1))) void*)gb,
            (__attribute__((address_space(3))) void*)&Bsl[1][ca * 512], 16, 0, 0);
    }
    // Full drain: slices 0/1 complete before the loop; steps 0/1's vmcnt(12) are
    // no-ops (6/12 outstanding); steady state from step 2 retires exactly one slice.
    asm volatile("s_waitcnt vmcnt(0)" ::: "memory");

    // slices 0..29: compute t, issue t+2, wait vmcnt(12) (t+1,t+2 in flight: 6+6)
    #pragma unroll 1
    for (int t2 = 0; t2 < 30; t2 += 3) {
        GRAM_STEP(afA, afC, 0, 2, (t2 + 2) * 32, 1, "s_waitcnt vmcnt(12)");
        GRAM_STEP(afB, afA, 1, 0, (t2 + 3) * 32, 1, "s_waitcnt vmcnt(12)");
        GRAM_STEP(afC, afB, 2, 1, (t2 + 4) * 32, 1, "s_waitcnt vmcnt(12)");
    }
    // epilogue: slice 30 (slice 31 still in flight), then slice 31
    GRAM_STEP(afA, afC, 0, 2, 0, 0, "s_waitcnt vmcnt(6)");
    GRAM_STEP(afB, afC, 1, 2, 0, 0, "s_waitcnt vmcnt(0)");

    const float* sqm = sq + m * NPTS;
    {
        int i0 = ti + (w << 4) + (lane >> 4) * 4;
        #pragma unroll
        for (int b = 0; b < 8; ++b) {
            int j = tj + b * 16 + (lane & 15);
            float sqj = sqm[j];
            #pragma unroll
            for (int r = 0; r < 4; ++r) {
                int i = i0 + r;
                float v = sqm[i] + sqj - 2.f * acc[b][r];
                if (i == j) v += 1e10f;
                dist[((size_t)m * NPTS + i) * NPTS + j] = v;
                if (bi != bj) dist[((size_t)m * NPTS + j) * NPTS + i] = v;
            }
        }
    }
}

// ---------------- K3: top-k (k=20 smallest), one wave per row, all-register ----------------
__global__ __launch_bounds__(256) void topk_kernel(const float* __restrict__ dist,
                                                   int* __restrict__ knn_idx) {
    int tid = threadIdx.x;
    int wave = tid >> 6, lane = tid & 63;
    int row = blockIdx.x * 4 + wave;
    const float* d = dist + (size_t)row * NPTS;
    float v[16];
    #pragma unroll
    for (int s = 0; s < 16; ++s) v[s] = d[s * 64 + lane];
    int myj = 0;
    for (int sel = 0; sel < KNN; ++sel) {
        float bv = v[0]; int bs = 0;
        #pragma unroll
        for (int s = 1; s < 16; ++s)
            if (v[s] < bv) { bv = v[s]; bs = s; }   // ascending s: lowest j locally on ties
        int bj = bs * 64 + lane;
        #pragma unroll
        for (int off = 1; off < 64; off <<= 1) {
            float ov = __shfl_xor(bv, off);
            int   oj = __shfl_xor(bj, off);
            if (ov < bv || (ov == bv && oj < bj)) { bv = ov; bj = oj; }
        }
        if ((bj & 63) == lane) v[bj >> 6] = 3e38f;  // owner clears
        if (lane == sel) myj = bj;
    }
    if (lane < KNN) knn_idx[(size_t)row * KNN + lane] = myj;
}

// ---------------- K5: t1 = relu(y_i + sum y_n + b1a); h1 = t1 @ W2a + b2a ----------------
// R12 version (proven): 512 threads, 8 waves/CU.
__global__ __launch_bounds__(512) void t1h1_kernel(const float* __restrict__ y,
                                                   const int* __restrict__ knn_idx,
                                                   const float* __restrict__ W,
                                                   const float* __restrict__ bias1,
                                                   const float* __restrict__ bias2,
                                                   float* __restrict__ h1) {
    int row0 = blockIdx.x * 64;
    int m = row0 >> 10;
    __shared__ int nb[64 * KNN];
    __shared__ float t1s[64][65];
    __shared__ float Ws[64][HID];
    __shared__ float b1s[HID], b2s[HID];
    int tid = threadIdx.x;                       // 0..511
    for (int k = tid; k < 64 * KNN; k += 512) nb[k] = knn_idx[(size_t)row0 * KNN + k];
    for (int k = tid; k < 64 * HID; k += 512) Ws[k >> 6][k & 63] = W[k];
    if (tid < HID) { b1s[tid] = bias1[tid]; b2s[tid] = bias2[tid]; }
    __syncthreads();
    {
        int r = tid >> 3, c0 = (tid & 7) * 8;    // 8 threads/row, 8 cols each
        const float* yr = y + (size_t)(row0 + r) * HID + c0;
        float4 a[2];
        #pragma unroll
        for (int q = 0; q < 2; ++q) a[q] = *(const float4*)&yr[q * 4];
        const float* ym = y + (size_t)(m << 10) * HID;
        #pragma unroll
        for (int t = 0; t < KNN; ++t) {
            const float* yn = ym + (size_t)nb[r * KNN + t] * HID + c0;
            #pragma unroll
            for (int q = 0; q < 2; ++q) {
                float4 v = *(const float4*)&yn[q * 4];
                a[q].x += v.x; a[q].y += v.y; a[q].z += v.z; a[q].w += v.w;
            }
        }
        #pragma unroll
        for (int q = 0; q < 2; ++q) {
            int c = c0 + q * 4;
            t1s[r][c + 0] = fmaxf(a[q].x + b1s[c + 0], 0.f);
            t1s[r][c + 1] = fmaxf(a[q].y + b1s[c + 1], 0.f);
            t1s[r][c + 2] = fmaxf(a[q].z + b1s[c + 2], 0.f);
            t1s[r][c + 3] = fmaxf(a[q].w + b1s[c + 3], 0.f);
        }
    }
    __syncthreads();
    int ty = tid >> 4, tx = tid & 15;            // rows ty*2..+1, cols tx*4..+3
    float acc[2][4];
    #pragma unroll
    for (int i = 0; i < 2; ++i)
        #pragma unroll
        for (int j = 0; j < 4; ++j) acc[i][j] = 0.f;
    #pragma unroll
    for (int k = 0; k < HID; ++k) {
        float a[2];
        #pragma unroll
        for (int ii = 0; ii < 2; ++ii) a[ii] = t1s[ty * 2 + ii][k];
        float4 w = *(const float4*)&Ws[k][tx * 4];
        #pragma unroll
        for (int ii = 0; ii < 2; ++ii) {
            acc[ii][0] += a[ii] * w.x;
            acc[ii][1] += a[ii] * w.y;
            acc[ii][2] += a[ii] * w.z;
            acc[ii][3] += a[ii] * w.w;
        }
    }
    #pragma unroll
    for (int ii = 0; ii < 2; ++ii) {
        float o[4];
        #pragma unroll
        for (int jj = 0; jj < 4; ++jj) o[jj] = acc[ii][jj] + b2s[tx * 4 + jj];
        *(float4*)&h1[(size_t)(row0 + ty * 2 + ii) * HID + tx * 4] = *(float4*)&o[0];
    }
}

// ---------------- K6: hs = h1_i + sum h1_n; t2 = relu(hs@W1b+b1b); z = t2@W2b+b2b ----------------
// R12 version (proven): 512 threads, 8 waves/CU.
__global__ __launch_bounds__(512) void t2z_kernel(const float* __restrict__ h1,
                                                  const int* __restrict__ knn_idx,
                                                  const float* __restrict__ W1,
                                                  const float* __restrict__ bias1,
                                                  const float* __restrict__ W2,
                                                  const float* __restrict__ bias2,
                                                  float* __restrict__ z) {
    int row0 = blockIdx.x * 64;
    int m = row0 >> 10;
    __shared__ int nb[64 * KNN];
    __shared__ float hs[64][65];
    __shared__ float t2s[64][65];
    __shared__ float Ws[64][HID];
    __shared__ float b1s[HID], b2s[HID];
    int tid = threadIdx.x;                       // 0..511
    for (int k = tid; k < 64 * KNN; k += 512) nb[k] = knn_idx[(size_t)row0 * KNN + k];
    for (int k = tid; k < 64 * HID; k += 512) Ws[k >> 6][k & 63] = W1[k];
    if (tid < HID) { b1s[tid] = bias1[tid]; b2s[tid] = bias2[tid]; }
    __syncthreads();
    {
        int r = tid >> 3, c0 = (tid & 7) * 8;
        const float* hr = h1 + (size_t)(row0 + r) * HID + c0;
        float4 a[2];
        #pragma unroll
        for (int q = 0; q < 2; ++q) a[q] = *(const float4*)&hr[q * 4];
        const float* hm = h1 + (size_t)(m << 10) * HID;
        #pragma unroll
        for (int t = 0; t < KNN; ++t) {
            const float* hn = hm + (size_t)nb[r * KNN + t] * HID + c0;
            #pragma unroll
            for (int q = 0; q < 2; ++q) {
                float4 v = *(const float4*)&hn[q * 4];
                a[q].x += v.x; a[q].y += v.y; a[q].z += v.z; a[q].w += v.w;
            }
        }
        #pragma unroll
        for (int q = 0; q < 2; ++q) *(float4*)&hs[r][c0 + q * 4] = a[q];
    }
    __syncthreads();
    int ty = tid >> 4, tx = tid & 15;
    float acc[2][4];
    #pragma unroll
    for (int i = 0; i < 2; ++i)
        #pragma unroll
        for (int j = 0; j < 4; ++j) acc[i][j] = 0.f;
    #pragma unroll
    for (int k = 0; k < HID; ++k) {
        float a[2];
        #pragma unroll
        for (int ii = 0; ii < 2; ++ii) a[ii] = hs[ty * 2 + ii][k];
        float4 w = *(const float4*)&Ws[k][tx * 4];
        #pragma unroll
        for (int ii = 0; ii < 2; ++ii) {
            acc[ii][0] += a[ii] * w.x;
            acc[ii][1] += a[ii] * w.y;
            acc[ii][2] += a[ii] * w.z;
            acc[ii][3] += a[ii] * w.w;
        }
    }
    #pragma unroll
    for (int ii = 0; ii < 2; ++ii)
        #pragma unroll
        for (int jj = 0; jj < 4; ++jj)
            t2s[ty * 2 + ii][tx * 4 + jj] = fmaxf(acc[ii][jj] + b1s[tx * 4 + jj], 0.f);
    __syncthreads();
    for (int k = tid; k < 64 * HID; k += 512) Ws[k >> 6][k & 63] = W2[k];
    __syncthreads();
    #pragma unroll
    for (int i = 0; i < 2; ++i)
        #pragma unroll
        for (int j = 0; j < 4; ++j) acc[i][j] = 0.f;
    #pragma unroll
    for (int k = 0; k < HID; ++k) {
        float a[2];
        #pragma unroll
        for (int ii = 0; ii < 2; ++ii) a[ii] = t2s[ty * 2 + ii][k];
        float4 w = *(const float4*)&Ws[k][tx * 4];
        #pragma unroll
        for (int ii = 0; ii < 2; ++ii) {
            acc[ii][0] += a[ii] * w.x;
            acc[ii][1] += a[ii] * w.y;
            acc[ii][2] += a[ii] * w.z;
            acc[ii][3] += a[ii] * w.w;
        }
    }
    #pragma unroll
    for (int ii = 0; ii < 2; ++ii) {
        float o[4];
        #pragma unroll
        for (int jj = 0; jj < 4; ++jj) o[jj] = acc[ii][jj] + b2s[tx * 4 + jj];
        *(float4*)&z[(size_t)(row0 + ty * 2 + ii) * HID + tx * 4] = *(float4*)&o[0];
    }
}

// ---------------- K7: sim = z1 @ z2^T (64x64 tiles, K=64) ----------------
__global__ __launch_bounds__(256) void sim_kernel(const float* __restrict__ z,
                                                  float* __restrict__ logits) {
    int bid = blockIdx.x;
    int b = bid >> 8;
    int tile = bid & 255;
    int ti = (tile >> 4) << 6;
    int tj = (tile & 15) << 6;
    const float* z1 = z + (size_t)b * NPTS * HID;
    const float* z2 = z + (size_t)(BATCH + b) * NPTS * HID;
    __shared__ float Z1[64][68];
    __shared__ float Z2[64][68];
    int tid = threadIdx.x;
    #pragma unroll
    for (int i = 0; i < 4; ++i) {
        int l = tid + i * 256;
        int r = l >> 4, c = (l & 15) * 4;
        *(float4*)&Z1[r][c] = *(const float4*)&z1[(size_t)(ti + r) * HID + c];
        *(float4*)&Z2[r][c] = *(const float4*)&z2[(size_t)(tj + r) * HID + c];
    }
    __syncthreads();
    int ty = tid >> 4, tx = tid & 15;
    float acc[4][4];
    #pragma unroll
    for (int i = 0; i < 4; ++i)
        #pragma unroll
        for (int j = 0; j < 4; ++j) acc[i][j] = 0.f;
    #pragma unroll
    for (int h = 0; h < HID; ++h) {
        float a[4], bb[4];
        #pragma unroll
        for (int ii = 0; ii < 4; ++ii) { a[ii] = Z1[ty * 4 + ii][h]; bb[ii] = Z2[tx * 4 + ii][h]; }
        #pragma unroll
        for (int ii = 0; ii < 4; ++ii)
            #pragma unroll
            for (int jj = 0; jj < 4; ++jj)
                acc[ii][jj] += a[ii] * bb[jj];
    }
    #pragma unroll
    for (int ii = 0; ii < 4; ++ii) {
        float* dst = logits + ((size_t)b * NPTS + ti + ty * 4 + ii) * NPTS + tj + tx * 4;
        *(float4*)&dst[0] = *(float4*)&acc[ii][0];
    }
}

// ---------------- K8: row softmax ----------------
__global__ __launch_bounds__(256) void softmax_kernel(const float* __restrict__ logits,
                                                      float* __restrict__ out) {
    int row = blockIdx.x;                         // 0..8191
    const float* L = logits + (size_t)row * NPTS;
    __shared__ float buf[NPTS];
    __shared__ float red[8];
    int tid = threadIdx.x;
    int wave = tid >> 6, lane = tid & 63;
    float mx = -3e38f;
    #pragma unroll
    for (int s = 0; s < 4; ++s) {
        float v = L[tid + s * 256];
        buf[tid + s * 256] = v;
        mx = fmaxf(mx, v);
    }
    #pragma unroll
    for (int off = 32; off > 0; off >>= 1) mx = fmaxf(mx, __shfl_down(mx, off));
    if (lane == 0) red[wave] = mx;
    __syncthreads();
    mx = fmaxf(fmaxf(red[0], red[1]), fmaxf(red[2], red[3]));
    float sum = 0.f;
    #pragma unroll
    for (int s = 0; s < 4; ++s) {
        float e = expf(buf[tid + s * 256] - mx);
        buf[tid + s * 256] = e;
        sum += e;
    }
    #pragma unroll
    for (int off = 32; off > 0; off >>= 1) sum += __shfl_down(sum, off);
    if (lane == 0) red[4 + wave] = sum;
    __syncthreads();
    float inv = 1.f / (red[4] + red[5] + red[6] + red[7]);
    #pragma unroll
    for (int s = 0; s < 4; ++s)
        out[(size_t)row * NPTS + tid + s * 256] = buf[tid + s * 256] * inv;
}

extern "C" void kernel_launch(void* const* d_in, const int* in_sizes, int n_in,
                              void* d_out, int out_size, void* d_ws, size_t ws_size,
                              hipStream_t stream) {
    const float* f1  = (const float*)d_in[0];
    const float* f2  = (const float*)d_in[1];
    const float* W1a = (const float*)d_in[2];
    const float* b1a = (const float*)d_in[3];
    const float* W2a = (const float*)d_in[4];
    const float* b2a = (const float*)d_in[5];
    const float* W1b = (const float*)d_in[6];
    const float* b1b = (const float*)d_in[7];
    const float* W2b = (const float*)d_in[8];
    const float* b2b = (const float*)d_in[9];
    float* out = (float*)d_out;

    // workspace: H packed (100.7MB) | dist (67.1MB, reused as sim logits) | sq | kidx | y | h1 | z
    char* ws = (char*)d_ws;
    unsigned short* H = (unsigned short*)ws;
    float* dist = (float*)(ws + (size_t)NMAT * NPTS * KPACK * sizeof(unsigned short));
    float* sq   = dist + (size_t)NMAT * NPTS * NPTS;
    int*   kidx = (int*)(sq + NMAT * NPTS);
    float* ybuf = (float*)(kidx + NMAT * NPTS * KNN);
    float* h1b  = ybuf + (size_t)NMAT * NPTS * HID;
    float* zb   = h1b + (size_t)NMAT * NPTS * HID;

    split_ymlp_kernel<<<NMAT * NPTS / 64, 512, 0, stream>>>(f1, f2, W1a, H, sq, ybuf);
    gram_mfma_kernel<<<NMAT * 36, 512, 0, stream>>>(H, sq, dist);
    topk_kernel<<<NMAT * NPTS / 4, 256, 0, stream>>>(dist, kidx);
    t1h1_kernel<<<NMAT * NPTS / 64, 512, 0, stream>>>(ybuf, kidx, W2a, b1a, b2a, h1b);
    t2z_kernel<<<NMAT * NPTS / 64, 512, 0, stream>>>(h1b, kidx, W1b, b1b, W2b, b2b, zb);
    sim_kernel<<<BATCH * 256, 256, 0, stream>>>(zb, dist);                      // dist := logits
    softmax_kernel<<<BATCH * NPTS, 256, 0, stream>>>(dist, out);
}